// Round 1
// baseline (567.441 us; speedup 1.0000x reference)
//
#include <hip/hip_runtime.h>
#include <math.h>

#define NB 8192
#define NC 128
#define TI 64
#define TJ 64
#define NJS 4
#define JCH (NB / NJS)

// ---------------------------------------------------------------- init
__global__ __launch_bounds__(256) void k_init(unsigned* __restrict__ gmax,
                                              unsigned* __restrict__ gmin,
                                              float* __restrict__ sums) {
    int i = blockIdx.x * 256 + threadIdx.x;
    if (i < NB) { gmax[i] = 0u; gmin[i] = 0x7f800000u; }  // 0, +inf
    if (i < 8) sums[i] = 0.0f;
}

// ---------------------------------------------------------------- row sum of squares
__global__ __launch_bounds__(256) void k_sq(const float* __restrict__ x,
                                            float* __restrict__ sq) {
    int row = blockIdx.x * 4 + (threadIdx.x >> 6);
    int l = threadIdx.x & 63;
    const float* xr = x + row * NC;
    float a = xr[l], b = xr[l + 64];
    float s = fmaf(a, a, b * b);
#pragma unroll
    for (int off = 32; off > 0; off >>= 1) s += __shfl_xor(s, off);
    if (l == 0) sq[row] = s;
}

// ---------------------------------------------------------------- triplet GEMM + fused reduce
// LDS layout: As/Bs stored with XOR swizzle: logical col c of row r lives at
// physical col (c ^ ((r>>2)&15)). Reads: a-reads broadcast over 16 lanes with
// 4 distinct banks; b-reads hit 16 distinct banks (conflict-free).
__global__ __launch_bounds__(256, 2) void k_trip(const float* __restrict__ x,
                                                 const int* __restrict__ tgt,
                                                 const float* __restrict__ sq,
                                                 unsigned* __restrict__ gmax,
                                                 unsigned* __restrict__ gmin) {
    __shared__ float As[TI][NC];
    __shared__ float Bs[TJ][NC];
    const int tid = threadIdx.x;
    const int tx = tid & 15, ty = tid >> 4;
    const int i0 = blockIdx.x * TI;
    const int jbase = blockIdx.y * JCH;

    // stage A tile (once per block), swizzled
#pragma unroll
    for (int m = 0; m < 8; ++m) {
        int idx = tid + 256 * m;
        int r = idx >> 5, c4 = idx & 31;
        float4 v = *(const float4*)(x + (i0 + r) * NC + c4 * 4);
        int s = (r >> 2) & 15, hi = s >> 2, lo = s & 3;
        float p[4];
        p[0 ^ lo] = v.x; p[1 ^ lo] = v.y; p[2 ^ lo] = v.z; p[3 ^ lo] = v.w;
        *(float4*)&As[r][4 * (c4 ^ hi)] = make_float4(p[0], p[1], p[2], p[3]);
    }

    float sqi[4]; int ti[4];
#pragma unroll
    for (int r = 0; r < 4; ++r) {
        int i = i0 + 4 * ty + r;
        sqi[r] = sq[i]; ti[r] = tgt[i];
    }

    float mp[4], mn[4];
#pragma unroll
    for (int r = 0; r < 4; ++r) { mp[r] = 0.0f; mn[r] = 3.0e38f; }

    for (int j0 = jbase; j0 < jbase + JCH; j0 += TJ) {
        __syncthreads();
#pragma unroll
        for (int m = 0; m < 8; ++m) {
            int idx = tid + 256 * m;
            int r = idx >> 5, c4 = idx & 31;
            float4 v = *(const float4*)(x + (j0 + r) * NC + c4 * 4);
            int s = (r >> 2) & 15, hi = s >> 2, lo = s & 3;
            float p[4];
            p[0 ^ lo] = v.x; p[1 ^ lo] = v.y; p[2 ^ lo] = v.z; p[3 ^ lo] = v.w;
            *(float4*)&Bs[r][4 * (c4 ^ hi)] = make_float4(p[0], p[1], p[2], p[3]);
        }
        __syncthreads();

        float acc[4][4];
#pragma unroll
        for (int r = 0; r < 4; ++r)
#pragma unroll
            for (int c = 0; c < 4; ++c) acc[r][c] = 0.0f;

#pragma unroll 8
        for (int k = 0; k < NC; ++k) {
            float a[4], b[4];
            int ka = k ^ ty, kb = k ^ tx;
#pragma unroll
            for (int r = 0; r < 4; ++r) a[r] = As[4 * ty + r][ka];
#pragma unroll
            for (int c = 0; c < 4; ++c) b[c] = Bs[4 * tx + c][kb];
#pragma unroll
            for (int r = 0; r < 4; ++r)
#pragma unroll
                for (int c = 0; c < 4; ++c) acc[r][c] = fmaf(a[r], b[c], acc[r][c]);
        }

        // epilogue: d^2 = sq_i + sq_j - 2*dot, clamp >=0, masked max/min
#pragma unroll
        for (int c = 0; c < 4; ++c) {
            int j = j0 + 4 * tx + c;
            float sqj = sq[j];
            int tj = tgt[j];
#pragma unroll
            for (int r = 0; r < 4; ++r) {
                float d2 = fmaxf(fmaf(-2.0f, acc[r][c], sqi[r] + sqj), 0.0f);
                bool pos = (tj == ti[r]);
                mp[r] = pos ? fmaxf(mp[r], d2) : mp[r];
                mn[r] = pos ? mn[r] : fminf(mn[r], d2);
            }
        }
    }

    // reduce across the 16 tx lanes (low 4 lane bits) sharing each anchor row
#pragma unroll
    for (int off = 1; off < 16; off <<= 1) {
#pragma unroll
        for (int r = 0; r < 4; ++r) {
            mp[r] = fmaxf(mp[r], __shfl_xor(mp[r], off));
            mn[r] = fminf(mn[r], __shfl_xor(mn[r], off));
        }
    }
    if (tx == 0) {
#pragma unroll
        for (int r = 0; r < 4; ++r) {
            int i = i0 + 4 * ty + r;
            atomicMax(&gmax[i], __float_as_uint(mp[r]));  // d2>=0 => uint order == float order
            atomicMin(&gmin[i], __float_as_uint(mn[r]));
        }
    }
}

// ---------------------------------------------------------------- hinge + sum
__global__ __launch_bounds__(256) void k_hinge(const unsigned* __restrict__ gmax,
                                               const unsigned* __restrict__ gmin,
                                               float* __restrict__ sums) {
    int i = blockIdx.x * 256 + threadIdx.x;
    float ap = sqrtf(fmaxf(__uint_as_float(gmax[i]), 1e-12f));
    float an = sqrtf(fmaxf(__uint_as_float(gmin[i]), 1e-12f));
    float h = fmaxf(ap - an + 0.3f, 0.0f);
#pragma unroll
    for (int off = 32; off > 0; off >>= 1) h += __shfl_xor(h, off);
    if ((threadIdx.x & 63) == 0) atomicAdd(&sums[0], h);
}

// ---------------------------------------------------------------- cross entropy (wave per row)
__global__ __launch_bounds__(256) void k_ce(const float* __restrict__ x,
                                            const int* __restrict__ tgt,
                                            float* __restrict__ sums) {
    int row = blockIdx.x * 4 + (threadIdx.x >> 6);
    int l = threadIdx.x & 63;
    const float* xr = x + row * NC;
    float a = xr[l], b = xr[l + 64];
    float m = fmaxf(a, b);
#pragma unroll
    for (int off = 32; off > 0; off >>= 1) m = fmaxf(m, __shfl_xor(m, off));
    float s = expf(a - m) + expf(b - m);
#pragma unroll
    for (int off = 32; off > 0; off >>= 1) s += __shfl_xor(s, off);
    int t = tgt[row];
    float tv = (t < 64) ? __shfl(a, t) : __shfl(b, t - 64);
    if (l == 0) atomicAdd(&sums[1], m + logf(s) - tv);
}

// ---------------------------------------------------------------- scalar tail (double)
__global__ void k_final(const float* __restrict__ sums, float* __restrict__ out) {
    const double E = 2.71828182845904523536;
    const double TAU = log(128.0);
    const double LAMd = 0.25;
    double l = (double)sums[0] / (double)NB;
    double ce = (double)sums[1] / (double)NB;
    double y = 0.5 * fmax(-2.0 / E, (l - TAU) / LAMd);
    // Lambert W, principal branch — reference's exact Halley scheme
    double p = sqrt(fmax(2.0 * (E * y + 1.0), 0.0));
    double wn = -1.0 + p - p * p / 3.0 + (11.0 / 72.0) * p * p * p;
    double w = (y < 0.0) ? wn : log1p(fmax(y, 0.0));
#pragma unroll
    for (int it = 0; it < 10; ++it) {
        double ew = exp(w);
        double f = w * ew - y;
        double wp1 = w + 1.0;
        w = w - f / (ew * wp1 - (w + 2.0) * f / (2.0 * wp1));
    }
    double sigma = exp(-w);
    double lg = log(sigma);
    double loss = (ce - TAU) * sigma + LAMd * lg * lg;
    out[0] = (float)(loss / (double)NB);
}

// ---------------------------------------------------------------- launcher
extern "C" void kernel_launch(void* const* d_in, const int* in_sizes, int n_in,
                              void* d_out, int out_size, void* d_ws, size_t ws_size,
                              hipStream_t stream) {
    const float* x = (const float*)d_in[0];
    const int* tgt = (const int*)d_in[1];
    float* out = (float*)d_out;

    // ws layout: [0..8) float sums | gmax[NB] u32 | gmin[NB] u32 | sq[NB] f32
    float* sums = (float*)d_ws;
    unsigned* gmax = (unsigned*)(sums + 8);
    unsigned* gmin = gmax + NB;
    float* sq = (float*)(gmin + NB);

    k_init<<<(NB + 255) / 256, 256, 0, stream>>>(gmax, gmin, sums);
    k_sq<<<NB / 4, 256, 0, stream>>>(x, sq);
    dim3 grid(NB / TI, NJS);
    k_trip<<<grid, 256, 0, stream>>>(x, tgt, sq, gmax, gmin);
    k_hinge<<<NB / 256, 256, 0, stream>>>(gmax, gmin, sums);
    k_ce<<<NB / 4, 256, 0, stream>>>(x, tgt, sums);
    k_final<<<1, 1, 0, stream>>>(sums, out);
}

// Round 2
// 93.756 us; speedup vs baseline: 6.0523x; 6.0523x over previous
//
#include <hip/hip_runtime.h>
#include <math.h>

#define NB 8192
#define NC 128
#define NJS 8          // j-slices (grid.y)
#define JPT 8          // j-tiles of 128 per block = (8192/128)/NJS

typedef short v8s __attribute__((ext_vector_type(8)));   // 8 bf16 (16 B)
typedef float v4f __attribute__((ext_vector_type(4)));

// fp32 -> bf16 round-to-nearest-even, returned in low 16 bits
__device__ inline unsigned bf16rne(float f) {
    unsigned u = __float_as_uint(f);
    return (u + 0x7fffu + ((u >> 16) & 1u)) >> 16;
}

// ---------------------------------------------------------------- prep:
// per row: bf16 cast (packed), sum-of-squares, CE term; init gmax/gmin.
__global__ __launch_bounds__(256) void k_prep(const float* __restrict__ x,
                                              const int* __restrict__ tgt,
                                              unsigned* __restrict__ xb,   // NB*64 uints (2 bf16 each)
                                              float* __restrict__ sq,
                                              float* __restrict__ ce,
                                              unsigned* __restrict__ gmax,
                                              unsigned* __restrict__ gmin) {
    int row = blockIdx.x * 4 + (threadIdx.x >> 6);
    int l = threadIdx.x & 63;
    float2 v = ((const float2*)(x + row * NC))[l];
    xb[row * 64 + l] = bf16rne(v.x) | (bf16rne(v.y) << 16);
    float ss = fmaf(v.x, v.x, v.y * v.y);
    float mx = fmaxf(v.x, v.y);
#pragma unroll
    for (int off = 32; off; off >>= 1) {
        ss += __shfl_xor(ss, off);
        mx = fmaxf(mx, __shfl_xor(mx, off));
    }
    float es = expf(v.x - mx) + expf(v.y - mx);
#pragma unroll
    for (int off = 32; off; off >>= 1) es += __shfl_xor(es, off);
    if (l == 0) {
        sq[row] = ss;
        ce[row] = mx + logf(es) - x[row * NC + tgt[row]];
        gmax[row] = 0u;
        gmin[row] = 0x7f800000u;   // +inf
    }
}

// ---------------------------------------------------------------- triplet:
// bf16 MFMA GEMM (dots) with fused hardest-pos/neg reduction.
// LDS tiles stored chunk-XOR-swizzled: 16-B chunk (r, c) holds global chunk
// (r, c ^ (r&7)) — swizzle applied on the GLOBAL source address because
// global_load_lds's LDS destination is fixed (wave base + lane*16).
__global__ __launch_bounds__(256, 2) void k_trip(const unsigned* __restrict__ xb,
                                                 const int* __restrict__ tgt,
                                                 const float* __restrict__ sq,
                                                 unsigned* __restrict__ gmax,
                                                 unsigned* __restrict__ gmin) {
    __shared__ short As[128 * 128];   // 32 KB
    __shared__ short Bs[128 * 128];   // 32 KB
    const int tid = threadIdx.x;
    const int lane = tid & 63;
    const int w = tid >> 6;           // wave 0..3
    const int rh = w >> 1;            // row half (64 rows)
    const int ch = w & 1;             // col half
    const int i0 = blockIdx.x * 128;

    // ---- stage A tile (once) ----
#pragma unroll
    for (int c = 0; c < 8; ++c) {
        int L = w * 512 + c * 64 + lane;          // chunk index 0..2047
        int r = L >> 4, cc = L & 15;
        const unsigned* src = xb + (size_t)(i0 + r) * 64 + (((cc ^ (r & 7)) << 2));
        __builtin_amdgcn_global_load_lds(
            (const __attribute__((address_space(1))) unsigned*)src,
            (__attribute__((address_space(3))) unsigned*)(As + (w * 512 + c * 64) * 8),
            16, 0, 0);
    }

    // ---- preload anchor targets for this lane's output rows ----
    int ti[4][4];
#pragma unroll
    for (int tm = 0; tm < 4; ++tm)
#pragma unroll
        for (int r = 0; r < 4; ++r) {
            int rowloc = rh * 64 + tm * 16 + ((lane >> 4) << 2) + r;
            ti[tm][r] = tgt[i0 + rowloc];
        }

    float mp[4][4], mn[4][4];
#pragma unroll
    for (int tm = 0; tm < 4; ++tm)
#pragma unroll
        for (int r = 0; r < 4; ++r) { mp[tm][r] = -3.0e38f; mn[tm][r] = 3.0e38f; }

    for (int jt = 0; jt < JPT; ++jt) {
        int j0 = (blockIdx.y * JPT + jt) * 128;
        __syncthreads();    // protect Bs from previous iteration's readers
#pragma unroll
        for (int c = 0; c < 8; ++c) {
            int L = w * 512 + c * 64 + lane;
            int r = L >> 4, cc = L & 15;
            const unsigned* src = xb + (size_t)(j0 + r) * 64 + (((cc ^ (r & 7)) << 2));
            __builtin_amdgcn_global_load_lds(
                (const __attribute__((address_space(1))) unsigned*)src,
                (__attribute__((address_space(3))) unsigned*)(Bs + (w * 512 + c * 64) * 8),
                16, 0, 0);
        }
        __syncthreads();    // drains vmcnt — A and B visible

        v4f acc[4][4];
        v4f z = {0.0f, 0.0f, 0.0f, 0.0f};
#pragma unroll
        for (int tm = 0; tm < 4; ++tm)
#pragma unroll
            for (int tn = 0; tn < 4; ++tn) acc[tm][tn] = z;

        const int m = lane & 15;
        const int quad = lane >> 4;
#pragma unroll
        for (int ks = 0; ks < 4; ++ks) {
            v8s a[4], b[4];
            int q = ks * 4 + quad;               // 16-B k-chunk index
#pragma unroll
            for (int tm = 0; tm < 4; ++tm) {
                int row = rh * 64 + tm * 16 + m;
                a[tm] = *(const v8s*)(As + row * 128 + ((q ^ (row & 7)) << 3));
            }
#pragma unroll
            for (int tn = 0; tn < 4; ++tn) {
                int col = ch * 64 + tn * 16 + m;
                b[tn] = *(const v8s*)(Bs + col * 128 + ((q ^ (col & 7)) << 3));
            }
#pragma unroll
            for (int tm = 0; tm < 4; ++tm)
#pragma unroll
                for (int tn = 0; tn < 4; ++tn)
                    acc[tm][tn] = __builtin_amdgcn_mfma_f32_16x16x32_bf16(
                        a[tm], b[tn], acc[tm][tn], 0, 0, 0);
        }

        // ---- fused epilogue: v = sqj - 2*dot  (sqi added once at the end) ----
#pragma unroll
        for (int tn = 0; tn < 4; ++tn) {
            int col = j0 + ch * 64 + tn * 16 + m;
            float sqj = sq[col];
            int tj = tgt[col];
#pragma unroll
            for (int tm = 0; tm < 4; ++tm)
#pragma unroll
                for (int r = 0; r < 4; ++r) {
                    float v = fmaf(-2.0f, acc[tm][tn][r], sqj);
                    bool pos = (tj == ti[tm][r]);
                    mp[tm][r] = fmaxf(mp[tm][r], pos ? v : -3.0e38f);
                    mn[tm][r] = fminf(mn[tm][r], pos ? 3.0e38f : v);
                }
        }
    }

    // ---- reduce across the 16 lanes (lane&15) sharing each output row ----
#pragma unroll
    for (int off = 1; off < 16; off <<= 1) {
#pragma unroll
        for (int tm = 0; tm < 4; ++tm)
#pragma unroll
            for (int r = 0; r < 4; ++r) {
                mp[tm][r] = fmaxf(mp[tm][r], __shfl_xor(mp[tm][r], off));
                mn[tm][r] = fminf(mn[tm][r], __shfl_xor(mn[tm][r], off));
            }
    }
    if ((lane & 15) == 0) {
#pragma unroll
        for (int tm = 0; tm < 4; ++tm)
#pragma unroll
            for (int r = 0; r < 4; ++r) {
                int i = i0 + rh * 64 + tm * 16 + ((lane >> 4) << 2) + r;
                float s = sq[i];
                float d2p = fmaxf(s + mp[tm][r], 0.0f);
                float d2n = fmaxf(s + mn[tm][r], 0.0f);
                atomicMax(gmax + i, __float_as_uint(d2p));   // >=0: uint order == float order
                atomicMin(gmin + i, __float_as_uint(d2n));
            }
    }
}

// ---------------------------------------------------------------- tail:
// hinge over rows + CE sum + Lambert-W scalar, single block.
__global__ __launch_bounds__(1024) void k_tail(const unsigned* __restrict__ gmax,
                                               const unsigned* __restrict__ gmin,
                                               const float* __restrict__ ce,
                                               float* __restrict__ out) {
    float hs = 0.0f, cs = 0.0f;
    for (int i = threadIdx.x; i < NB; i += 1024) {
        float ap = sqrtf(fmaxf(__uint_as_float(gmax[i]), 1e-12f));
        float an = sqrtf(fmaxf(__uint_as_float(gmin[i]), 1e-12f));
        hs += fmaxf(ap - an + 0.3f, 0.0f);
        cs += ce[i];
    }
#pragma unroll
    for (int off = 32; off; off >>= 1) {
        hs += __shfl_xor(hs, off);
        cs += __shfl_xor(cs, off);
    }
    __shared__ float sh[16], sc[16];
    int wv = threadIdx.x >> 6;
    if ((threadIdx.x & 63) == 0) { sh[wv] = hs; sc[wv] = cs; }
    __syncthreads();
    if (threadIdx.x == 0) {
        double H = 0.0, Cs = 0.0;
        for (int k = 0; k < 16; ++k) { H += sh[k]; Cs += sc[k]; }
        const double E = 2.71828182845904523536;
        const double TAU = log(128.0);
        const double LAMd = 0.25;
        double l = H / (double)NB;
        double cev = Cs / (double)NB;
        double y = 0.5 * fmax(-2.0 / E, (l - TAU) / LAMd);
        double p = sqrt(fmax(2.0 * (E * y + 1.0), 0.0));
        double wn = -1.0 + p - p * p / 3.0 + (11.0 / 72.0) * p * p * p;
        double wlw = (y < 0.0) ? wn : log1p(fmax(y, 0.0));
#pragma unroll
        for (int it = 0; it < 10; ++it) {
            double ew = exp(wlw);
            double f = wlw * ew - y;
            double wp1 = wlw + 1.0;
            wlw = wlw - f / (ew * wp1 - (wlw + 2.0) * f / (2.0 * wp1));
        }
        double sigma = exp(-wlw);
        double lg = log(sigma);
        double loss = (cev - TAU) * sigma + LAMd * lg * lg;
        out[0] = (float)(loss / (double)NB);
    }
}

// ---------------------------------------------------------------- launcher
extern "C" void kernel_launch(void* const* d_in, const int* in_sizes, int n_in,
                              void* d_out, int out_size, void* d_ws, size_t ws_size,
                              hipStream_t stream) {
    const float* x = (const float*)d_in[0];
    const int* tgt = (const int*)d_in[1];
    float* out = (float*)d_out;

    // ws: xb (NB*64 u32 = 2 MB) | sq (NB f32) | ce (NB f32) | gmax | gmin
    unsigned* xb = (unsigned*)d_ws;
    float* sq = (float*)(xb + (size_t)NB * 64);
    float* ce = sq + NB;
    unsigned* gmax = (unsigned*)(ce + NB);
    unsigned* gmin = gmax + NB;

    k_prep<<<NB / 4, 256, 0, stream>>>(x, tgt, xb, sq, ce, gmax, gmin);
    dim3 grid(NB / 128, NJS);
    k_trip<<<grid, 256, 0, stream>>>(xb, tgt, sq, gmax, gmin);
    k_tail<<<1, 1024, 0, stream>>>(gmax, gmin, ce, out);
}